// Round 9
// baseline (899.580 us; speedup 1.0000x reference)
//
#include <hip/hip_runtime.h>
#include <hip/hip_bf16.h>
#include <hip/hip_fp16.h>
#include <math.h>

#define EPS 1e-8f

typedef __attribute__((ext_vector_type(8))) short bf16x8;
typedef __attribute__((ext_vector_type(8))) _Float16 f16x8;
typedef __attribute__((ext_vector_type(4))) float f32x4;
typedef __attribute__((ext_vector_type(16))) float f32x16;

__device__ static inline unsigned short f2bf(float f) {
    __hip_bfloat16 h = __float2bfloat16(f);
    return *reinterpret_cast<unsigned short*>(&h);
}
__device__ static inline unsigned short f2h(float f) {
    __half h = __float2half(f);
    return *reinterpret_cast<unsigned short*>(&h);
}

__device__ static inline void gld_lds16(const void* g, void* l) {
    __builtin_amdgcn_global_load_lds((const __attribute__((address_space(1))) void*)g,
                                     (__attribute__((address_space(3))) void*)l, 16, 0, 0);
}

__device__ static inline void h8tof(uint4 w, float* f) {
    float2 a = __half22float2(*(__half2*)&w.x);
    float2 b = __half22float2(*(__half2*)&w.y);
    float2 c = __half22float2(*(__half2*)&w.z);
    float2 d = __half22float2(*(__half2*)&w.w);
    f[0] = a.x; f[1] = a.y; f[2] = b.x; f[3] = b.y;
    f[4] = c.x; f[5] = c.y; f[6] = d.x; f[7] = d.y;
}

// ---------------------------------------------------------------------------
// Fused prep: x->fp16 (401408) | w1->fp16 padded 96 (24576) | cw->fp16 (1474560)
__global__ void k_prep(const float* __restrict__ x, unsigned short* __restrict__ xh,
                       const float* __restrict__ w1, unsigned short* __restrict__ wt1h,
                       const float* __restrict__ cw, __half* __restrict__ cwh) {
    int idx = blockIdx.x * 256 + threadIdx.x;
    if (idx < 401408) {
        xh[idx] = f2h(x[idx]);
    } else if (idx < 401408 + 24576) {
        int j = idx - 401408;
        int n = j / 96, k = j % 96;
        wt1h[j] = (k < 81) ? f2h(w1[n * 81 + k]) : (unsigned short)0;
    } else {
        int j = idx - 401408 - 24576;   // < 1474560
        cwh[j] = __float2half(cw[j]);
    }
}

// conv2 weights -> bf16, layout wt2t[oc][q*256+ic], via LDS transpose.
__global__ __launch_bounds__(256) void k_tw2(const float* __restrict__ pw,
                                             unsigned short* __restrict__ wt2t) {
    __shared__ unsigned short lds[20736];
    const int oc = blockIdx.x, t = threadIdx.x;
    const float* src = pw + (size_t)oc * 20736;
#pragma unroll
    for (int it = 0; it < 81; ++it) {
        int j = it * 256 + t;                  // j = ic*81 + q
        lds[j] = f2bf(src[j]);
    }
    __syncthreads();
    unsigned short* dst = wt2t + (size_t)oc * 20736;
#pragma unroll
    for (int it = 0; it < 81; ++it) {
        int j = it * 256 + t;                  // j = q*256 + ic
        int q = j >> 8, ic = j & 255;
        dst[j] = lds[ic * 81 + q];
    }
}

// ---------------------------------------------------------------------------
// conv1 as fp16 MFMA GEMM: M=204800, N=256, K=81 pad 96. Output h1 bf16 NHWC.
__global__ __launch_bounds__(256) void k_conv1(const unsigned short* __restrict__ xh,
                                               const unsigned short* __restrict__ wt1h,
                                               const float* __restrict__ b1,
                                               unsigned short* __restrict__ h1) {
    __shared__ unsigned short Asm[128 * 104];
    __shared__ unsigned short Bsm[128 * 104];
    const int tid = threadIdx.x;
    const int wave = tid >> 6, lane = tid & 63;
    const int ln15 = lane & 15, quad = lane >> 4;
    const int m0 = blockIdx.x * 128;
    const int n0 = blockIdx.y * 128;
    const int wm = (wave >> 1) * 64, wn = (wave & 1) * 64;

    for (int c = tid; c < 1536; c += 256) {
        int r = c / 12, ch = c % 12;
        uint4 v = *(const uint4*)(wt1h + (size_t)(n0 + r) * 96 + ch * 8);
        *(uint4*)(&Bsm[r * 104 + ch * 8]) = v;
    }
    for (int s = 0; s < 5; ++s) {
        int id = s * 256 + tid;
        if (id < 1152) {
            int m_l = id & 127, kh = id >> 7;
            int m = m0 + m_l;
            int b = m / 400, sp = m % 400;
            int oh = sp / 20, ow = sp % 20;
            const unsigned short* src = xh + b * 784 + (oh + kh) * 28 + ow;
            unsigned short* drow = &Asm[m_l * 104 + kh * 9];
#pragma unroll
            for (int w = 0; w < 9; ++w) drow[w] = src[w];
        }
    }
    for (int z = tid; z < 1920; z += 256) {
        int r = z / 15, kk = 81 + z % 15;
        Asm[r * 104 + kk] = 0;
    }
    __syncthreads();

    f32x4 acc[4][4];
#pragma unroll
    for (int i = 0; i < 4; ++i)
#pragma unroll
        for (int j = 0; j < 4; ++j) acc[i][j] = (f32x4)(0.f);

#pragma unroll
    for (int ks = 0; ks < 3; ++ks) {
        int k0 = (ks * 4 + quad) * 8;
        f16x8 af[4], bfr[4];
#pragma unroll
        for (int i = 0; i < 4; ++i)
            af[i] = *(const f16x8*)&Asm[(wm + i * 16 + ln15) * 104 + k0];
#pragma unroll
        for (int j = 0; j < 4; ++j)
            bfr[j] = *(const f16x8*)&Bsm[(wn + j * 16 + ln15) * 104 + k0];
#pragma unroll
        for (int i = 0; i < 4; ++i)
#pragma unroll
            for (int j = 0; j < 4; ++j)
                acc[i][j] = __builtin_amdgcn_mfma_f32_16x16x32_f16(
                    af[i], bfr[j], acc[i][j], 0, 0, 0);
    }

    float bias[4];
#pragma unroll
    for (int j = 0; j < 4; ++j) bias[j] = b1[n0 + wn + j * 16 + ln15];
#pragma unroll
    for (int i = 0; i < 4; ++i) {
#pragma unroll
        for (int r = 0; r < 4; ++r) {
            int m = m0 + wm + i * 16 + quad * 4 + r;
            unsigned short* dst = h1 + (size_t)m * 256 + n0 + wn;
#pragma unroll
            for (int j = 0; j < 4; ++j) {
                float v = acc[i][j][r] + bias[j];
                dst[j * 16 + ln15] = f2bf(v > 0.f ? v : 0.f);
            }
        }
    }
}

// ---------------------------------------------------------------------------
// conv2 bf16 MFMA GEMM (round-7 proven): BM=128 BN=128 BK=64, split-K=6,
// 32x32x16 MFMA, A+B staged via gld_lds w16 + XOR swizzle, m-fastest grid.
__global__ __launch_bounds__(256) void k_conv2(const unsigned short* __restrict__ h1,
                                               const unsigned short* __restrict__ wt2t,
                                               float* __restrict__ h2a) {
    __shared__ short Asm[128 * 64];
    __shared__ short Bsm[128 * 64];

    const int tid  = threadIdx.x;
    const int wave = tid >> 6, lane = tid & 63;
    const int ln31 = lane & 31, ln7 = lane & 7, khalf = lane >> 5;
    const int m0 = blockIdx.x * 128;
    const int n0 = blockIdx.y * 128;
    const int zz = blockIdx.z;
    const int kt0 = zz * 54;                  // 324 kt total / 6
    const int wm = (wave >> 1) * 64, wn = (wave & 1) * 64;

    const int rbase = wave * 32 + (lane >> 3);
    const int cswz8 = ((lane & 7) ^ ((lane >> 3) & 7)) * 8;

    size_t aptr[4];
    size_t bptr[4];
#pragma unroll
    for (int s = 0; s < 4; ++s) {
        int r = rbase + s * 8;
        int m = m0 + r;
        int b = m / 36, sp = m % 36;
        int oh = sp / 6, ow = sp % 6;
        aptr[s] = (size_t)((b * 20 + 2 * oh) * 20 + 2 * ow) * 256 + cswz8;
        bptr[s] = (size_t)(n0 + r) * 20736 + cswz8;
    }
    short* alds = &Asm[(wave * 32) * 64 + lane * 8];
    short* blds = &Bsm[(wave * 32) * 64 + lane * 8];

    f32x16 acc[2][2];
#pragma unroll
    for (int i = 0; i < 2; ++i)
#pragma unroll
        for (int j = 0; j < 2; ++j) acc[i][j] = (f32x16)(0.f);

    int q0 = kt0 >> 2;
    int kh = q0 / 9, kw = q0 - kh * 9;
    int pix = (kh * 20 + kw) * 256;

    for (int kt = kt0; kt < kt0 + 54; ++kt) {
        size_t aoff = (size_t)pix + ((kt & 3) << 6);
        size_t boff = (size_t)kt << 6;
#pragma unroll
        for (int s = 0; s < 4; ++s)
            gld_lds16(h1 + aptr[s] + aoff, alds + s * 512);
#pragma unroll
        for (int s = 0; s < 4; ++s)
            gld_lds16(wt2t + bptr[s] + boff, blds + s * 512);
        __syncthreads();
#pragma unroll
        for (int ks = 0; ks < 4; ++ks) {
            int slot = ((ks << 1) + khalf) ^ ln7;
            bf16x8 af[2], bfr[2];
#pragma unroll
            for (int i = 0; i < 2; ++i)
                af[i] = *(const bf16x8*)&Asm[(wm + i * 32 + ln31) * 64 + slot * 8];
#pragma unroll
            for (int j = 0; j < 2; ++j)
                bfr[j] = *(const bf16x8*)&Bsm[(wn + j * 32 + ln31) * 64 + slot * 8];
#pragma unroll
            for (int i = 0; i < 2; ++i)
#pragma unroll
                for (int j = 0; j < 2; ++j)
                    acc[i][j] = __builtin_amdgcn_mfma_f32_32x32x16_bf16(
                        af[i], bfr[j], acc[i][j], 0, 0, 0);
        }
        __syncthreads();
        if ((kt & 3) == 3) {
            if (kw == 8) { kw = 0; ++kh; pix += 12 * 256; }
            else         { ++kw;       pix += 256; }
        }
    }

    float* zs = h2a + (size_t)zz * 4718592;
#pragma unroll
    for (int i = 0; i < 2; ++i) {
#pragma unroll
        for (int j = 0; j < 2; ++j) {
#pragma unroll
            for (int reg = 0; reg < 16; ++reg) {
                int row = (reg & 3) + 8 * (reg >> 2) + 4 * khalf;
                int m = m0 + wm + i * 32 + row;
                zs[(size_t)m * 256 + n0 + wn + j * 32 + ln31] = acc[i][j][reg];
            }
        }
    }
}

// ---------------------------------------------------------------------------
// Sum 6 split-K slices + bias, squash capsules, write u[b][i][8] in fp16.
__global__ __launch_bounds__(256) void k_squash(const float* __restrict__ h2a,
                                                const float* __restrict__ pb,
                                                unsigned short* __restrict__ u) {
    __shared__ float tile[36 * 260];
    const int tid = threadIdx.x;
    const int b = blockIdx.x;
    const float* base = h2a + (size_t)b * 36 * 256;
    for (int idx = tid; idx < 9216; idx += 256) {
        int sp = idx >> 8, c = idx & 255;
        float v = pb[c];
#pragma unroll
        for (int z = 0; z < 6; ++z) v += base[(size_t)z * 4718592 + sp * 256 + c];
        tile[sp * 260 + c] = v;
    }
    __syncthreads();
    for (int i2 = tid; i2 < 1152; i2 += 256) {
        int f0 = i2 * 8;
        float val[8];
        float n2 = 0.f;
#pragma unroll
        for (int e = 0; e < 8; ++e) {
            int f = f0 + e;
            int c = f / 36, sp = f - c * 36;
            val[e] = tile[sp * 260 + c];
            n2 += val[e] * val[e];
        }
        float n = sqrtf(n2);
        float s = n2 / (1.f + n2) / (n + EPS);
        unsigned short o8[8];
#pragma unroll
        for (int e = 0; e < 8; ++e) o8[e] = f2h(val[e] * s);
        *(uint4*)(u + (size_t)b * 9216 + f0) = *(uint4*)o8;
    }
}

// ---------------------------------------------------------------------------
// Dynamic routing v4: recompute xh from L2-resident cwh (2.95 MB) each sweep;
// no materialized x_hat. One block per b, 640 threads = 10 o x 64 lanes.
// Sweep A: s0 -> v1. Sweeps B,C (pass 1,2): per 192-i group compute
// dots -> barrier -> per-i softmax -> barrier -> accumulate with xh[3][16]
// held in registers. u (fp16) staged in LDS.
__global__ __launch_bounds__(640) void k_routing(const unsigned short* __restrict__ u,
                                                 const __half* __restrict__ cwh,
                                                 float* __restrict__ out) {
    __shared__ unsigned short ush[9216];     // 18.4 KB (u fp16)
    __shared__ float dots[10][192];          // 7.5 KB per-group scratch
    __shared__ float sv[10][16];
    __shared__ float vsum[10][16];
    __shared__ float scale_sh[10];
    const int t = threadIdx.x;
    const int b = blockIdx.x;
    const int o = t >> 6, lane = t & 63;

    {
        const uint4* src = (const uint4*)(u + (size_t)b * 9216);
        uint4* dst = (uint4*)ush;
        for (int idx = t; idx < 1152; idx += 640) dst[idx] = src[idx];
    }
    __syncthreads();

    // ---- Sweep A: s0[o][d] = sum_i xh(o,i,d); v1 = squash(0.1*s0)
    {
        float s_loc[16];
#pragma unroll
        for (int d = 0; d < 16; ++d) s_loc[d] = 0.f;
        for (int chunk = 0; chunk < 18; ++chunk) {
            int i = chunk * 64 + lane;
            float ui[8];
            h8tof(((const uint4*)ush)[i], ui);
            const uint4* wp = (const uint4*)(cwh + ((size_t)(o * 1152 + i) << 7));
#pragma unroll
            for (int d = 0; d < 16; ++d) {
                float f[8];
                h8tof(wp[d], f);
                s_loc[d] += f[0] * ui[0] + f[1] * ui[1] + f[2] * ui[2] + f[3] * ui[3]
                          + f[4] * ui[4] + f[5] * ui[5] + f[6] * ui[6] + f[7] * ui[7];
            }
        }
#pragma unroll
        for (int off = 32; off > 0; off >>= 1)
#pragma unroll
            for (int d = 0; d < 16; ++d) s_loc[d] += __shfl_down(s_loc[d], off, 64);
        if (lane == 0) {
#pragma unroll
            for (int d = 0; d < 16; ++d) sv[o][d] = 0.1f * s_loc[d];
        }
    }
    __syncthreads();
    if (t < 10) {
        float n2 = 0.f;
#pragma unroll
        for (int d = 0; d < 16; ++d) n2 += sv[t][d] * sv[t][d];
        float n = sqrtf(n2);
        scale_sh[t] = n2 / (1.f + n2) / (n + EPS);
    }
    __syncthreads();
    if (t < 160) vsum[t >> 4][t & 15] = sv[t >> 4][t & 15] * scale_sh[t >> 4];
    __syncthreads();

    // ---- Sweeps B,C: routing passes 1,2
    for (int pass = 1; pass <= 2; ++pass) {
        float vs[16];
#pragma unroll
        for (int d = 0; d < 16; ++d) vs[d] = vsum[o][d];
        float s_loc[16];
#pragma unroll
        for (int d = 0; d < 16; ++d) s_loc[d] = 0.f;

        for (int g = 0; g < 6; ++g) {
            float xh3[3][16];
#pragma unroll
            for (int j = 0; j < 3; ++j) {
                int i = g * 192 + j * 64 + lane;
                float ui[8];
                h8tof(((const uint4*)ush)[i], ui);
                const uint4* wp = (const uint4*)(cwh + ((size_t)(o * 1152 + i) << 7));
                float dd = 0.f;
#pragma unroll
                for (int d = 0; d < 16; ++d) {
                    float f[8];
                    h8tof(wp[d], f);
                    float x = f[0] * ui[0] + f[1] * ui[1] + f[2] * ui[2] + f[3] * ui[3]
                            + f[4] * ui[4] + f[5] * ui[5] + f[6] * ui[6] + f[7] * ui[7];
                    xh3[j][d] = x;
                    dd += vs[d] * x;
                }
                dots[o][j * 64 + lane] = dd;
            }
            __syncthreads();
            if (t < 192) {
                float dv[10];
#pragma unroll
                for (int oo = 0; oo < 10; ++oo) dv[oo] = dots[oo][t];
                float mx = dv[0];
#pragma unroll
                for (int oo = 1; oo < 10; ++oo) mx = fmaxf(mx, dv[oo]);
                float se = 0.f;
#pragma unroll
                for (int oo = 0; oo < 10; ++oo) { dv[oo] = __expf(dv[oo] - mx); se += dv[oo]; }
                float si = 1.f / se;
#pragma unroll
                for (int oo = 0; oo < 10; ++oo) dots[oo][t] = dv[oo] * si;
            }
            __syncthreads();
#pragma unroll
            for (int j = 0; j < 3; ++j) {
                float c = dots[o][j * 64 + lane];
#pragma unroll
                for (int d = 0; d < 16; ++d) s_loc[d] += c * xh3[j][d];
            }
            __syncthreads();   // protect dots before next group's writes
        }
#pragma unroll
        for (int off = 32; off > 0; off >>= 1)
#pragma unroll
            for (int d = 0; d < 16; ++d) s_loc[d] += __shfl_down(s_loc[d], off, 64);
        if (lane == 0) {
#pragma unroll
            for (int d = 0; d < 16; ++d) sv[o][d] = s_loc[d];
        }
        __syncthreads();
        if (pass == 1) {
            if (t < 10) {
                float n2 = 0.f;
#pragma unroll
                for (int d = 0; d < 16; ++d) n2 += sv[t][d] * sv[t][d];
                float n = sqrtf(n2);
                scale_sh[t] = n2 / (1.f + n2) / (n + EPS);
            }
            __syncthreads();
            if (t < 160) {
                int oo = t >> 4, d = t & 15;
                vsum[oo][d] += sv[oo][d] * scale_sh[oo];
            }
            __syncthreads();
        } else {
            if (t < 10) {
                float n2 = 0.f;
#pragma unroll
                for (int d = 0; d < 16; ++d) n2 += sv[t][d] * sv[t][d];
                float n = sqrtf(n2);
                out[b * 10 + t] = (n2 / (1.f + n2)) * (n / (n + EPS));
            }
        }
    }
}

// ---------------------------------------------------------------------------
extern "C" void kernel_launch(void* const* d_in, const int* in_sizes, int n_in,
                              void* d_out, int out_size, void* d_ws, size_t ws_size,
                              hipStream_t stream) {
    const float* x  = (const float*)d_in[0];   // [512,1,28,28]
    const float* w1 = (const float*)d_in[1];   // [256,1,9,9]
    const float* b1 = (const float*)d_in[2];   // [256]
    const float* pw = (const float*)d_in[3];   // [256,256,9,9]
    const float* pb = (const float*)d_in[4];   // [256]
    const float* cw = (const float*)d_in[5];   // [10,1152,16,8]
    float* out = (float*)d_out;                // [512,10]

    char* ws = (char*)d_ws;
    unsigned short* h1   = (unsigned short*)ws;                    // 104,857,600 B @ 0
    float*          h2a  = (float*)(ws + 104857600);               // 113,246,208 B -> 218,103,808
    unsigned short* wt2t = (unsigned short*)(ws + 218103808);      //  10,616,832 B -> 228,720,640
    unsigned short* u    = (unsigned short*)(ws + 228720640);      //   9,437,184 B -> 238,157,824
    __half*         cwh  = (__half*)(ws + 238157824);              //   2,949,120 B -> 241,106,944
    unsigned short* xh16 = (unsigned short*)(ws + 241106944);      //     802,816 B -> 241,909,760
    unsigned short* wt1h = (unsigned short*)(ws + 241909760);      //      49,152 B -> 241,958,912

    k_prep<<<7424, 256, 0, stream>>>(x, xh16, w1, wt1h, cw, cwh);
    k_tw2<<<256, 256, 0, stream>>>(pw, wt2t);
    k_conv1<<<dim3(1600, 2), 256, 0, stream>>>(xh16, wt1h, b1, h1);
    k_conv2<<<dim3(144, 2, 6), 256, 0, stream>>>(h1, wt2t, h2a);
    k_squash<<<512, 256, 0, stream>>>(h2a, pb, u);
    k_routing<<<512, 640, 0, stream>>>(u, cwh, out);
}

// Round 10
// 603.237 us; speedup vs baseline: 1.4913x; 1.4913x over previous
//
#include <hip/hip_runtime.h>
#include <hip/hip_bf16.h>
#include <hip/hip_fp16.h>
#include <math.h>

#define EPS 1e-8f

typedef __attribute__((ext_vector_type(8))) short bf16x8;
typedef __attribute__((ext_vector_type(8))) _Float16 f16x8;
typedef __attribute__((ext_vector_type(4))) float f32x4;
typedef __attribute__((ext_vector_type(16))) float f32x16;

__device__ static inline unsigned short f2bf(float f) {
    __hip_bfloat16 h = __float2bfloat16(f);
    return *reinterpret_cast<unsigned short*>(&h);
}
__device__ static inline unsigned short f2h(float f) {
    __half h = __float2half(f);
    return *reinterpret_cast<unsigned short*>(&h);
}

__device__ static inline void gld_lds16(const void* g, void* l) {
    __builtin_amdgcn_global_load_lds((const __attribute__((address_space(1))) void*)g,
                                     (__attribute__((address_space(3))) void*)l, 16, 0, 0);
}

__device__ static inline void h8tof(uint4 w, float* f) {
    float2 a = __half22float2(*(__half2*)&w.x);
    float2 b = __half22float2(*(__half2*)&w.y);
    float2 c = __half22float2(*(__half2*)&w.z);
    float2 d = __half22float2(*(__half2*)&w.w);
    f[0] = a.x; f[1] = a.y; f[2] = b.x; f[3] = b.y;
    f[4] = c.x; f[5] = c.y; f[6] = d.x; f[7] = d.y;
}

// ---------------------------------------------------------------------------
// Fused prep: x->fp16 (401408) | w1->fp16 padded 96 (24576) | cw->fp16 (1474560)
__global__ void k_prep(const float* __restrict__ x, unsigned short* __restrict__ xh,
                       const float* __restrict__ w1, unsigned short* __restrict__ wt1h,
                       const float* __restrict__ cw, __half* __restrict__ cwh) {
    int idx = blockIdx.x * 256 + threadIdx.x;
    if (idx < 401408) {
        xh[idx] = f2h(x[idx]);
    } else if (idx < 401408 + 24576) {
        int j = idx - 401408;
        int n = j / 96, k = j % 96;
        wt1h[j] = (k < 81) ? f2h(w1[n * 81 + k]) : (unsigned short)0;
    } else {
        int j = idx - 401408 - 24576;   // < 1474560
        cwh[j] = __float2half(cw[j]);
    }
}

// conv2 weights -> bf16, layout wt2t[oc][q*256+ic], via LDS transpose.
__global__ __launch_bounds__(256) void k_tw2(const float* __restrict__ pw,
                                             unsigned short* __restrict__ wt2t) {
    __shared__ unsigned short lds[20736];
    const int oc = blockIdx.x, t = threadIdx.x;
    const float* src = pw + (size_t)oc * 20736;
#pragma unroll
    for (int it = 0; it < 81; ++it) {
        int j = it * 256 + t;                  // j = ic*81 + q
        lds[j] = f2bf(src[j]);
    }
    __syncthreads();
    unsigned short* dst = wt2t + (size_t)oc * 20736;
#pragma unroll
    for (int it = 0; it < 81; ++it) {
        int j = it * 256 + t;                  // j = q*256 + ic
        int q = j >> 8, ic = j & 255;
        dst[j] = lds[ic * 81 + q];
    }
}

// ---------------------------------------------------------------------------
// conv1 as fp16 MFMA GEMM: M=204800, N=256, K=81 pad 96. Output h1 bf16 NHWC.
__global__ __launch_bounds__(256) void k_conv1(const unsigned short* __restrict__ xh,
                                               const unsigned short* __restrict__ wt1h,
                                               const float* __restrict__ b1,
                                               unsigned short* __restrict__ h1) {
    __shared__ unsigned short Asm[128 * 104];
    __shared__ unsigned short Bsm[128 * 104];
    const int tid = threadIdx.x;
    const int wave = tid >> 6, lane = tid & 63;
    const int ln15 = lane & 15, quad = lane >> 4;
    const int m0 = blockIdx.x * 128;
    const int n0 = blockIdx.y * 128;
    const int wm = (wave >> 1) * 64, wn = (wave & 1) * 64;

    for (int c = tid; c < 1536; c += 256) {
        int r = c / 12, ch = c % 12;
        uint4 v = *(const uint4*)(wt1h + (size_t)(n0 + r) * 96 + ch * 8);
        *(uint4*)(&Bsm[r * 104 + ch * 8]) = v;
    }
    for (int s = 0; s < 5; ++s) {
        int id = s * 256 + tid;
        if (id < 1152) {
            int m_l = id & 127, kh = id >> 7;
            int m = m0 + m_l;
            int b = m / 400, sp = m % 400;
            int oh = sp / 20, ow = sp % 20;
            const unsigned short* src = xh + b * 784 + (oh + kh) * 28 + ow;
            unsigned short* drow = &Asm[m_l * 104 + kh * 9];
#pragma unroll
            for (int w = 0; w < 9; ++w) drow[w] = src[w];
        }
    }
    for (int z = tid; z < 1920; z += 256) {
        int r = z / 15, kk = 81 + z % 15;
        Asm[r * 104 + kk] = 0;
    }
    __syncthreads();

    f32x4 acc[4][4];
#pragma unroll
    for (int i = 0; i < 4; ++i)
#pragma unroll
        for (int j = 0; j < 4; ++j) acc[i][j] = (f32x4)(0.f);

#pragma unroll
    for (int ks = 0; ks < 3; ++ks) {
        int k0 = (ks * 4 + quad) * 8;
        f16x8 af[4], bfr[4];
#pragma unroll
        for (int i = 0; i < 4; ++i)
            af[i] = *(const f16x8*)&Asm[(wm + i * 16 + ln15) * 104 + k0];
#pragma unroll
        for (int j = 0; j < 4; ++j)
            bfr[j] = *(const f16x8*)&Bsm[(wn + j * 16 + ln15) * 104 + k0];
#pragma unroll
        for (int i = 0; i < 4; ++i)
#pragma unroll
            for (int j = 0; j < 4; ++j)
                acc[i][j] = __builtin_amdgcn_mfma_f32_16x16x32_f16(
                    af[i], bfr[j], acc[i][j], 0, 0, 0);
    }

    float bias[4];
#pragma unroll
    for (int j = 0; j < 4; ++j) bias[j] = b1[n0 + wn + j * 16 + ln15];
#pragma unroll
    for (int i = 0; i < 4; ++i) {
#pragma unroll
        for (int r = 0; r < 4; ++r) {
            int m = m0 + wm + i * 16 + quad * 4 + r;
            unsigned short* dst = h1 + (size_t)m * 256 + n0 + wn;
#pragma unroll
            for (int j = 0; j < 4; ++j) {
                float v = acc[i][j][r] + bias[j];
                dst[j * 16 + ln15] = f2bf(v > 0.f ? v : 0.f);
            }
        }
    }
}

// ---------------------------------------------------------------------------
// conv2 bf16 MFMA GEMM (round-7 proven): BM=128 BN=128 BK=64, split-K=6,
// 32x32x16 MFMA, A+B staged via gld_lds w16 + XOR swizzle, m-fastest grid.
__global__ __launch_bounds__(256) void k_conv2(const unsigned short* __restrict__ h1,
                                               const unsigned short* __restrict__ wt2t,
                                               float* __restrict__ h2a) {
    __shared__ short Asm[128 * 64];
    __shared__ short Bsm[128 * 64];

    const int tid  = threadIdx.x;
    const int wave = tid >> 6, lane = tid & 63;
    const int ln31 = lane & 31, ln7 = lane & 7, khalf = lane >> 5;
    const int m0 = blockIdx.x * 128;
    const int n0 = blockIdx.y * 128;
    const int zz = blockIdx.z;
    const int kt0 = zz * 54;                  // 324 kt total / 6
    const int wm = (wave >> 1) * 64, wn = (wave & 1) * 64;

    const int rbase = wave * 32 + (lane >> 3);
    const int cswz8 = ((lane & 7) ^ ((lane >> 3) & 7)) * 8;

    size_t aptr[4];
    size_t bptr[4];
#pragma unroll
    for (int s = 0; s < 4; ++s) {
        int r = rbase + s * 8;
        int m = m0 + r;
        int b = m / 36, sp = m % 36;
        int oh = sp / 6, ow = sp % 6;
        aptr[s] = (size_t)((b * 20 + 2 * oh) * 20 + 2 * ow) * 256 + cswz8;
        bptr[s] = (size_t)(n0 + r) * 20736 + cswz8;
    }
    short* alds = &Asm[(wave * 32) * 64 + lane * 8];
    short* blds = &Bsm[(wave * 32) * 64 + lane * 8];

    f32x16 acc[2][2];
#pragma unroll
    for (int i = 0; i < 2; ++i)
#pragma unroll
        for (int j = 0; j < 2; ++j) acc[i][j] = (f32x16)(0.f);

    int q0 = kt0 >> 2;
    int kh = q0 / 9, kw = q0 - kh * 9;
    int pix = (kh * 20 + kw) * 256;

    for (int kt = kt0; kt < kt0 + 54; ++kt) {
        size_t aoff = (size_t)pix + ((kt & 3) << 6);
        size_t boff = (size_t)kt << 6;
#pragma unroll
        for (int s = 0; s < 4; ++s)
            gld_lds16(h1 + aptr[s] + aoff, alds + s * 512);
#pragma unroll
        for (int s = 0; s < 4; ++s)
            gld_lds16(wt2t + bptr[s] + boff, blds + s * 512);
        __syncthreads();
#pragma unroll
        for (int ks = 0; ks < 4; ++ks) {
            int slot = ((ks << 1) + khalf) ^ ln7;
            bf16x8 af[2], bfr[2];
#pragma unroll
            for (int i = 0; i < 2; ++i)
                af[i] = *(const bf16x8*)&Asm[(wm + i * 32 + ln31) * 64 + slot * 8];
#pragma unroll
            for (int j = 0; j < 2; ++j)
                bfr[j] = *(const bf16x8*)&Bsm[(wn + j * 32 + ln31) * 64 + slot * 8];
#pragma unroll
            for (int i = 0; i < 2; ++i)
#pragma unroll
                for (int j = 0; j < 2; ++j)
                    acc[i][j] = __builtin_amdgcn_mfma_f32_32x32x16_bf16(
                        af[i], bfr[j], acc[i][j], 0, 0, 0);
        }
        __syncthreads();
        if ((kt & 3) == 3) {
            if (kw == 8) { kw = 0; ++kh; pix += 12 * 256; }
            else         { ++kw;       pix += 256; }
        }
    }

    float* zs = h2a + (size_t)zz * 4718592;
#pragma unroll
    for (int i = 0; i < 2; ++i) {
#pragma unroll
        for (int j = 0; j < 2; ++j) {
#pragma unroll
            for (int reg = 0; reg < 16; ++reg) {
                int row = (reg & 3) + 8 * (reg >> 2) + 4 * khalf;
                int m = m0 + wm + i * 32 + row;
                zs[(size_t)m * 256 + n0 + wn + j * 32 + ln31] = acc[i][j][reg];
            }
        }
    }
}

// ---------------------------------------------------------------------------
// Sum 6 split-K slices + bias, squash capsules, write u[b][i][8] in fp16.
__global__ __launch_bounds__(256) void k_squash(const float* __restrict__ h2a,
                                                const float* __restrict__ pb,
                                                unsigned short* __restrict__ u) {
    __shared__ float tile[36 * 260];
    const int tid = threadIdx.x;
    const int b = blockIdx.x;
    const float* base = h2a + (size_t)b * 36 * 256;
    for (int idx = tid; idx < 9216; idx += 256) {
        int sp = idx >> 8, c = idx & 255;
        float v = pb[c];
#pragma unroll
        for (int z = 0; z < 6; ++z) v += base[(size_t)z * 4718592 + sp * 256 + c];
        tile[sp * 260 + c] = v;
    }
    __syncthreads();
    for (int i2 = tid; i2 < 1152; i2 += 256) {
        int f0 = i2 * 8;
        float val[8];
        float n2 = 0.f;
#pragma unroll
        for (int e = 0; e < 8; ++e) {
            int f = f0 + e;
            int c = f / 36, sp = f - c * 36;
            val[e] = tile[sp * 260 + c];
            n2 += val[e] * val[e];
        }
        float n = sqrtf(n2);
        float s = n2 / (1.f + n2) / (n + EPS);
        unsigned short o8[8];
#pragma unroll
        for (int e = 0; e < 8; ++e) o8[e] = f2h(val[e] * s);
        *(uint4*)(u + (size_t)b * 9216 + f0) = *(uint4*)o8;
    }
}

// ---------------------------------------------------------------------------
// Materialize x_hat[b][o][i][d] fp16 + s0[b][o][d] = sum_i xh.
// Grid (512,10), 256 threads, NO LDS u-staging (u fp16 is L3-hot, 9.4 MB):
// 5120 independent blocks for latency hiding; barrier only for final reduce.
__global__ __launch_bounds__(256) void k_xhat(const unsigned short* __restrict__ u,
                                              const __half* __restrict__ cwh,
                                              __half* __restrict__ xhat,
                                              float* __restrict__ s0) {
    __shared__ float part[4][16];
    const int b = blockIdx.x, o = blockIdx.y;
    const int t = threadIdx.x;
    const uint4* ub = (const uint4*)(u + (size_t)b * 9216);
    float s_loc[16];
#pragma unroll
    for (int d = 0; d < 16; ++d) s_loc[d] = 0.f;

    for (int i = t; i < 1152; i += 256) {
        float ui[8];
        h8tof(ub[i], ui);
        const uint4* wp = (const uint4*)(cwh + ((size_t)(o * 1152 + i) << 7));
        unsigned short xv[16];
#pragma unroll
        for (int d = 0; d < 16; ++d) {
            float f[8];
            h8tof(wp[d], f);
            float xh = f[0] * ui[0] + f[1] * ui[1] + f[2] * ui[2] + f[3] * ui[3]
                     + f[4] * ui[4] + f[5] * ui[5] + f[6] * ui[6] + f[7] * ui[7];
            s_loc[d] += xh;
            xv[d] = f2h(xh);
        }
        __half* dst = xhat + ((size_t)((b * 10 + o) * 1152 + i)) * 16;
        *(uint4*)dst       = *(uint4*)xv;
        *(uint4*)(dst + 8) = *(uint4*)(xv + 8);
    }
#pragma unroll
    for (int off = 32; off > 0; off >>= 1)
#pragma unroll
        for (int d = 0; d < 16; ++d) s_loc[d] += __shfl_down(s_loc[d], off, 64);
    if ((t & 63) == 0) {
#pragma unroll
        for (int d = 0; d < 16; ++d) part[t >> 6][d] = s_loc[d];
    }
    __syncthreads();
    if (t < 16)
        s0[(b * 10 + o) * 16 + t] = part[0][t] + part[1][t] + part[2][t] + part[3][t];
}

// ---------------------------------------------------------------------------
// Dynamic routing v3 (proven): fp16 x_hat, pass0 via s0, one fused sweep/pass.
__global__ __launch_bounds__(640) void k_routing(const __half* __restrict__ xhat,
                                                 const float* __restrict__ s0,
                                                 float* __restrict__ out) {
    __shared__ float dots[10][1152];
    __shared__ float sv[10][16];
    __shared__ float vsum[10][16];
    __shared__ float scale_sh[10];
    const int t = threadIdx.x;
    const int b = blockIdx.x;
    const int o = t >> 6, lane = t & 63;
    const __half* xb = xhat + ((size_t)(b * 10 + o) * 1152) * 16;

    if (t < 160) {
        int oo = t >> 4, d = t & 15;
        sv[oo][d] = 0.1f * s0[(b * 10 + oo) * 16 + d];
    }
    __syncthreads();
    if (t < 10) {
        float n2 = 0.f;
#pragma unroll
        for (int d = 0; d < 16; ++d) n2 += sv[t][d] * sv[t][d];
        float n = sqrtf(n2);
        scale_sh[t] = n2 / (1.f + n2) / (n + EPS);
    }
    __syncthreads();
    if (t < 160) vsum[t >> 4][t & 15] = sv[t >> 4][t & 15] * scale_sh[t >> 4];
    __syncthreads();

    for (int pass = 1; pass <= 2; ++pass) {
        float vs[16];
#pragma unroll
        for (int d = 0; d < 16; ++d) vs[d] = vsum[o][d];
        float s_loc[16];
#pragma unroll
        for (int d = 0; d < 16; ++d) s_loc[d] = 0.f;

        for (int g = 0; g < 6; ++g) {
            uint4 xq[3][2];
#pragma unroll
            for (int j = 0; j < 3; ++j) {
                int i = g * 192 + j * 64 + lane;
                const uint4* p = (const uint4*)(xb + (size_t)i * 16);
                xq[j][0] = p[0];
                xq[j][1] = p[1];
                float f0[8], f1[8];
                h8tof(xq[j][0], f0);
                h8tof(xq[j][1], f1);
                float dd = 0.f;
#pragma unroll
                for (int d = 0; d < 8; ++d) dd += vs[d] * f0[d] + vs[d + 8] * f1[d];
                dots[o][i] = dd;
            }
            __syncthreads();
            if (t < 192) {
                int i = g * 192 + t;
                float dv[10];
#pragma unroll
                for (int oo = 0; oo < 10; ++oo) dv[oo] = dots[oo][i];
                float mx = dv[0];
#pragma unroll
                for (int oo = 1; oo < 10; ++oo) mx = fmaxf(mx, dv[oo]);
                float se = 0.f;
#pragma unroll
                for (int oo = 0; oo < 10; ++oo) { dv[oo] = __expf(dv[oo] - mx); se += dv[oo]; }
                float si = 1.f / se;
#pragma unroll
                for (int oo = 0; oo < 10; ++oo) dots[oo][i] = dv[oo] * si;
            }
            __syncthreads();
#pragma unroll
            for (int j = 0; j < 3; ++j) {
                int i = g * 192 + j * 64 + lane;
                float c = dots[o][i];
                float f0[8], f1[8];
                h8tof(xq[j][0], f0);
                h8tof(xq[j][1], f1);
#pragma unroll
                for (int d = 0; d < 8; ++d) {
                    s_loc[d]     += c * f0[d];
                    s_loc[d + 8] += c * f1[d];
                }
            }
        }
#pragma unroll
        for (int off = 32; off > 0; off >>= 1)
#pragma unroll
            for (int d = 0; d < 16; ++d) s_loc[d] += __shfl_down(s_loc[d], off, 64);
        if (lane == 0) {
#pragma unroll
            for (int d = 0; d < 16; ++d) sv[o][d] = s_loc[d];
        }
        __syncthreads();
        if (pass == 1) {
            if (t < 10) {
                float n2 = 0.f;
#pragma unroll
                for (int d = 0; d < 16; ++d) n2 += sv[t][d] * sv[t][d];
                float n = sqrtf(n2);
                scale_sh[t] = n2 / (1.f + n2) / (n + EPS);
            }
            __syncthreads();
            if (t < 160) {
                int oo = t >> 4, d = t & 15;
                vsum[oo][d] += sv[oo][d] * scale_sh[oo];
            }
            __syncthreads();
        } else {
            if (t < 10) {
                float n2 = 0.f;
#pragma unroll
                for (int d = 0; d < 16; ++d) n2 += sv[t][d] * sv[t][d];
                float n = sqrtf(n2);
                out[b * 10 + t] = (n2 / (1.f + n2)) * (n / (n + EPS));
            }
        }
    }
}

// ---------------------------------------------------------------------------
extern "C" void kernel_launch(void* const* d_in, const int* in_sizes, int n_in,
                              void* d_out, int out_size, void* d_ws, size_t ws_size,
                              hipStream_t stream) {
    const float* x  = (const float*)d_in[0];   // [512,1,28,28]
    const float* w1 = (const float*)d_in[1];   // [256,1,9,9]
    const float* b1 = (const float*)d_in[2];   // [256]
    const float* pw = (const float*)d_in[3];   // [256,256,9,9]
    const float* pb = (const float*)d_in[4];   // [256]
    const float* cw = (const float*)d_in[5];   // [10,1152,16,8]
    float* out = (float*)d_out;                // [512,10]

    char* ws = (char*)d_ws;
    // xhat (189 MB) aliases h1 (100 MB) + head of h2a -- both dead before
    // k_xhat writes. wt2t/u/etc sit past the alias region.
    unsigned short* h1   = (unsigned short*)ws;                    // 104,857,600 B @ 0
    float*          h2a  = (float*)(ws + 104857600);               // 113,246,208 B -> 218,103,808
    unsigned short* wt2t = (unsigned short*)(ws + 218103808);      //  10,616,832 B -> 228,720,640
    __half*         xhat = (__half*)ws;                            // 188,743,680 B @ 0 (alias)
    unsigned short* u    = (unsigned short*)(ws + 228720640);      //   9,437,184 B -> 238,157,824
    __half*         cwh  = (__half*)(ws + 238157824);              //   2,949,120 B -> 241,106,944
    unsigned short* xh16 = (unsigned short*)(ws + 241106944);      //     802,816 B -> 241,909,760
    unsigned short* wt1h = (unsigned short*)(ws + 241909760);      //      49,152 B -> 241,958,912
    float*          s0   = (float*)(ws + 241958912);               //     327,680 B -> 242,286,592

    k_prep<<<7424, 256, 0, stream>>>(x, xh16, w1, wt1h, cw, cwh);
    k_tw2<<<256, 256, 0, stream>>>(pw, wt2t);
    k_conv1<<<dim3(1600, 2), 256, 0, stream>>>(xh16, wt1h, b1, h1);
    k_conv2<<<dim3(144, 2, 6), 256, 0, stream>>>(h1, wt2t, h2a);
    k_squash<<<512, 256, 0, stream>>>(h2a, pb, u);
    k_xhat<<<dim3(512, 10), 256, 0, stream>>>(u, cwh, xhat, s0);
    k_routing<<<512, 640, 0, stream>>>(xhat, s0, out);
}